// Round 7
// baseline (119.751 us; speedup 1.0000x reference)
//
#include <hip/hip_runtime.h>
#include <math.h>

#define BB 4
#define SQL 512
#define SKL 512
#define HH 256
#define AA 128

// 2 * log2(e): Qt/Kt pre-scaled so the score loop feeds v_exp_f32 (2^x) directly.
#define PRESCALE 2.8853900817779268f
#define LOG2E    1.4426950408889634f

__device__ inline void fma4(float4& a, float s, const float4& b) {
    a.x = fmaf(s, b.x, a.x); a.y = fmaf(s, b.y, a.y);
    a.z = fmaf(s, b.z, a.z); a.w = fmaf(s, b.w, a.w);
}

// DPP add: x + dpp_move(x). Stays on the VALU pipe (no ds_swizzle / lgkm).
template <int CTRL>
__device__ __forceinline__ float dpp_add(float x) {
    int m = __builtin_amdgcn_update_dpp(__float_as_int(x), __float_as_int(x),
                                        CTRL, 0xF, 0xF, false);
    return x + __int_as_float(m);
}
// Sum over each aligned 16-lane group (one DPP row):
//   xor1 = quad_perm:[1,0,3,2] (0xB1), xor2 = quad_perm:[2,3,0,1] (0x4E),
//   xor4 = row_half_mirror (0x141), xor8 = row_mirror (0x140).
__device__ __forceinline__ float red16(float x) {
    x = dpp_add<0xB1>(x);
    x = dpp_add<0x4E>(x);
    x = dpp_add<0x141>(x);
    x = dpp_add<0x140>(x);
    return x;
}

// ---------------------------------------------------------------------------
// Kernel 1 "prep": Qt = PRESCALE*(Q@W_q), Kt = PRESCALE*(K@W_k), VW = V@W_o.
// (unchanged from verified version)
// ---------------------------------------------------------------------------
__global__ __launch_bounds__(256) void prep_kernel(
    const float* __restrict__ Q, const float* __restrict__ K,
    const float* __restrict__ V,
    const float* __restrict__ Wq, const float* __restrict__ Wk,
    const float* __restrict__ Wo,
    float* __restrict__ Qt, float* __restrict__ Kt, float* __restrict__ VW)
{
    __shared__ float rows[16 * HH];    // 16 KB
    __shared__ float wl[64 * 128];     // 32 KB
    int tid = threadIdx.x;
    int bid = blockIdx.x;

    const float* X; const float* W; float* Y;
    int ldW, ldY, col0, r0; float scale;
    if (bid < 128)      { X=Q; W=Wq; Y=Qt; ldW=AA; ldY=AA; col0=0; r0=bid*16;       scale=PRESCALE; }
    else if (bid < 256) { X=K; W=Wk; Y=Kt; ldW=AA; ldY=AA; col0=0; r0=(bid-128)*16; scale=PRESCALE; }
    else { int b2=bid-256; X=V; W=Wo; Y=VW; ldW=HH; ldY=HH; col0=(b2&1)*128; r0=(b2>>1)*16; scale=1.0f; }

    {
        const float4* Xv = (const float4*)(X + (size_t)r0 * HH);
        float4* rv = (float4*)rows;
        rv[tid]       = Xv[tid];
        rv[tid + 256] = Xv[tid + 256];
        rv[tid + 512] = Xv[tid + 512];
        rv[tid + 768] = Xv[tid + 768];
    }

    int r  = tid >> 5;
    int c4 = tid & 31;
    float4 accA = {0.f,0.f,0.f,0.f}, accB = {0.f,0.f,0.f,0.f};

    for (int ch = 0; ch < 4; ++ch) {
        __syncthreads();
        {
            const float* Wbase = W + (size_t)(ch * 64) * ldW + col0;
            float4* wv = (float4*)wl;
            #pragma unroll
            for (int it = 0; it < 8; ++it) {
                int l = tid + it * 256;
                wv[l] = *(const float4*)(Wbase + (size_t)(l >> 5) * ldW + ((l & 31) << 2));
            }
        }
        __syncthreads();
        const float* rrowA = rows + r * HH + ch * 64;
        const float* rrowB = rows + (r + 8) * HH + ch * 64;
        #pragma unroll 4
        for (int h4 = 0; h4 < 16; ++h4) {
            float4 ra = *(const float4*)(rrowA + h4 * 4);
            float4 rb = *(const float4*)(rrowB + h4 * 4);
            const float* wbase = wl + (h4 * 4) * 128 + (c4 << 2);
            float4 w0 = *(const float4*)(wbase);
            float4 w1 = *(const float4*)(wbase + 128);
            float4 w2 = *(const float4*)(wbase + 256);
            float4 w3 = *(const float4*)(wbase + 384);
            fma4(accA, ra.x, w0); fma4(accA, ra.y, w1);
            fma4(accA, ra.z, w2); fma4(accA, ra.w, w3);
            fma4(accB, rb.x, w0); fma4(accB, rb.y, w1);
            fma4(accB, rb.z, w2); fma4(accB, rb.w, w3);
        }
    }
    accA.x *= scale; accA.y *= scale; accA.z *= scale; accA.w *= scale;
    accB.x *= scale; accB.y *= scale; accB.z *= scale; accB.w *= scale;
    *(float4*)(Y + (size_t)(r0 + r)     * ldY + col0 + (c4 << 2)) = accA;
    *(float4*)(Y + (size_t)(r0 + r + 8) * ldY + col0 + (c4 << 2)) = accB;
}

// ---------------------------------------------------------------------------
// Kernel 2: fused scores + softmax + (weights @ VW + b_o).
// grid = B*SQ/8 = 256 blocks x 512 thr (8 waves). 8 q-rows per block.
//   score[q][k] = S_all - sum_a 2*v[a] * rcp(Ek*Eq + 1),  Ek=2^kt, Eq=2^qt.
// ALL hot state in NAMED float4 registers (macro-generated) — R2's VGPR=100
// proved the array/lambda version put Eq and kt in scratch (SROA failure);
// this version has no pointer-indirected locals at all.
// Per-thread a-slice = 8 (16-lane a-groups, red16 via 4 DPP adds) -> Eq is
// 16 named float4 (64 VGPR), worst-case live ~130 VGPR, no spill possible.
// kt prefetched one chunk ahead into named regs (na/nb).
// NOTE: (Eq##HB##Qi).COMP needs the parens — without them the lexer forms
// the pp-number "0.COMP" before pasting and the build breaks.
// ---------------------------------------------------------------------------
#define FORQ(OP) OP(0) OP(1) OP(2) OP(3) OP(4) OP(5) OP(6) OP(7)

__global__ __launch_bounds__(512, 2) void score_kernel(
    const float* __restrict__ Qt, const float* __restrict__ Kt,
    const float* __restrict__ v,  const float* __restrict__ VW,
    const float* __restrict__ bo,
    float* __restrict__ weights,  float* __restrict__ out)
{
    __shared__ float score[8][SKL];      // 16 KB
    __shared__ float pout[8][4][HH];     // 32 KB   (total 48 KB)

    int tid = threadIdx.x;
    int b  = blockIdx.x >> 6;            // 64 blocks per batch
    int q0 = (blockIdx.x & 63) << 3;     // 8 q-rows per block
    int ag = tid & 15;                   // a-range [8ag, 8ag+8)
    int kl = tid >> 4;                   // k within 32-chunk (0..31)

    // 2*v fragment: 8 floats in 2 named float4
    float4 v2a, v2b;
    {
        const float4* vp = (const float4*)(v + ag * 8);
        v2a = vp[0]; v2b = vp[1];
        v2a.x *= 2.f; v2a.y *= 2.f; v2a.z *= 2.f; v2a.w *= 2.f;
        v2b.x *= 2.f; v2b.y *= 2.f; v2b.z *= 2.f; v2b.w *= 2.f;
    }

    // Eq = 2^(Qt prescaled): 8 q-rows x 8 a -> 16 named float4
#define DECL_EQ(Qi) float4 EqA##Qi, EqB##Qi;
    FORQ(DECL_EQ)
#define LOAD_EQ(Qi) { \
        const float4* qp = (const float4*)(Qt + (size_t)(b * SQL + q0 + Qi) * AA + ag * 8); \
        float4 t0 = qp[0], t1 = qp[1]; \
        (EqA##Qi).x = __builtin_amdgcn_exp2f(t0.x); (EqA##Qi).y = __builtin_amdgcn_exp2f(t0.y); \
        (EqA##Qi).z = __builtin_amdgcn_exp2f(t0.z); (EqA##Qi).w = __builtin_amdgcn_exp2f(t0.w); \
        (EqB##Qi).x = __builtin_amdgcn_exp2f(t1.x); (EqB##Qi).y = __builtin_amdgcn_exp2f(t1.y); \
        (EqB##Qi).z = __builtin_amdgcn_exp2f(t1.z); (EqB##Qi).w = __builtin_amdgcn_exp2f(t1.w); }
    FORQ(LOAD_EQ)

    // S_all = sum_a v[a]  (v2 = 2v, so 0.5 * red16)
    float S_all;
    {
        float ls = (v2a.x + v2a.y) + (v2a.z + v2a.w)
                 + (v2b.x + v2b.y) + (v2b.z + v2b.w);
        S_all = 0.5f * red16(ls);
    }

    const float4* ktp = (const float4*)(Kt + (size_t)b * SKL * AA);

    // ---- main loop: 16 chunks x 32 k-rows; named-reg prefetch ----
    {
        float4 ka = ktp[(size_t)kl * (AA / 4) + ag * 2];
        float4 kb = ktp[(size_t)kl * (AA / 4) + ag * 2 + 1];
        #pragma unroll 1
        for (int c = 0; c < 16; ++c) {
            float4 na, nb;
            if (c < 15) {
                int kn = (c + 1) * 32 + kl;
                na = ktp[(size_t)kn * (AA / 4) + ag * 2];
                nb = ktp[(size_t)kn * (AA / 4) + ag * 2 + 1];
            }
#define DECL_P(Qi) float p##Qi = 0.f;
            FORQ(DECL_P)
#define STEP(KE, VE, HB, COMP) { \
            float Ek = __builtin_amdgcn_exp2f(KE); \
            p0 = fmaf(VE, __builtin_amdgcn_rcpf(fmaf(Ek, (Eq##HB##0).COMP, 1.0f)), p0); \
            p1 = fmaf(VE, __builtin_amdgcn_rcpf(fmaf(Ek, (Eq##HB##1).COMP, 1.0f)), p1); \
            p2 = fmaf(VE, __builtin_amdgcn_rcpf(fmaf(Ek, (Eq##HB##2).COMP, 1.0f)), p2); \
            p3 = fmaf(VE, __builtin_amdgcn_rcpf(fmaf(Ek, (Eq##HB##3).COMP, 1.0f)), p3); \
            p4 = fmaf(VE, __builtin_amdgcn_rcpf(fmaf(Ek, (Eq##HB##4).COMP, 1.0f)), p4); \
            p5 = fmaf(VE, __builtin_amdgcn_rcpf(fmaf(Ek, (Eq##HB##5).COMP, 1.0f)), p5); \
            p6 = fmaf(VE, __builtin_amdgcn_rcpf(fmaf(Ek, (Eq##HB##6).COMP, 1.0f)), p6); \
            p7 = fmaf(VE, __builtin_amdgcn_rcpf(fmaf(Ek, (Eq##HB##7).COMP, 1.0f)), p7); }
            STEP(ka.x, v2a.x, A, x) STEP(ka.y, v2a.y, A, y)
            STEP(ka.z, v2a.z, A, z) STEP(ka.w, v2a.w, A, w)
            STEP(kb.x, v2b.x, B, x) STEP(kb.y, v2b.y, B, y)
            STEP(kb.z, v2b.z, B, z) STEP(kb.w, v2b.w, B, w)
#define RED_P(Qi) p##Qi = red16(p##Qi);
            FORQ(RED_P)
            if (ag == 0) {
                int k = c * 32 + kl;
#define STORE_P(Qi) score[Qi][k] = (S_all - p##Qi) * LOG2E;
                FORQ(STORE_P)
            }
            ka = na; kb = nb;
        }
    }
    __syncthreads();

    // ---- softmax (no max pass: |score| bounded by sum|2v| ~ 11.3 nat) ----
    int wave = tid >> 6, lane = tid & 63;
    {
        int qi = wave;                   // 8 waves, one q-row each
        float ssum = 0.f;
        #pragma unroll
        for (int it = 0; it < 2; ++it) {
            int k0 = it * 256 + (lane << 2);
            float4 sv = *(float4*)&score[qi][k0];
            sv.x = __builtin_amdgcn_exp2f(sv.x);
            sv.y = __builtin_amdgcn_exp2f(sv.y);
            sv.z = __builtin_amdgcn_exp2f(sv.z);
            sv.w = __builtin_amdgcn_exp2f(sv.w);
            *(float4*)&score[qi][k0] = sv;
            ssum += (sv.x + sv.y) + (sv.z + sv.w);
        }
        #pragma unroll
        for (int off = 32; off; off >>= 1) ssum += __shfl_xor(ssum, off);
        float rinv = 1.0f / ssum;
        size_t rowoff = (size_t)(b * SQL + q0 + qi) * SKL;
        #pragma unroll
        for (int it = 0; it < 2; ++it) {
            int k0 = it * 256 + (lane << 2);
            float4 sv = *(float4*)&score[qi][k0];
            sv.x *= rinv; sv.y *= rinv; sv.z *= rinv; sv.w *= rinv;
            *(float4*)&score[qi][k0] = sv;
            *(float4*)(weights + rowoff + k0) = sv;
        }
    }
    __syncthreads();

    // ---- epilogue: wave w owns k in [64w, 64w+64); one VW pass serves 8 q
#define DECL_ACC(Qi) float4 acc##Qi = {0.f, 0.f, 0.f, 0.f};
    FORQ(DECL_ACC)
    {
        const float4* VWb = (const float4*)(VW + (size_t)b * SKL * HH);
        int kbase = wave * 64;
        #pragma unroll 2
        for (int k4 = 0; k4 < 16; ++k4) {
            int kk = kbase + k4 * 4;
#define DECL_W(Qi) float4 w##Qi = *(const float4*)&score[Qi][kk];
            FORQ(DECL_W)
            float4 vw;
            vw = VWb[(size_t)(kk + 0) * (HH / 4) + lane];
#define FMA_X(Qi) fma4(acc##Qi, (w##Qi).x, vw);
            FORQ(FMA_X)
            vw = VWb[(size_t)(kk + 1) * (HH / 4) + lane];
#define FMA_Y(Qi) fma4(acc##Qi, (w##Qi).y, vw);
            FORQ(FMA_Y)
            vw = VWb[(size_t)(kk + 2) * (HH / 4) + lane];
#define FMA_Z(Qi) fma4(acc##Qi, (w##Qi).z, vw);
            FORQ(FMA_Z)
            vw = VWb[(size_t)(kk + 3) * (HH / 4) + lane];
#define FMA_W(Qi) fma4(acc##Qi, (w##Qi).w, vw);
            FORQ(FMA_W)
        }
    }

    // ---- LDS tree-reduce over the 8 waves, 2 rounds of 4 q-rows ----
    int h  = tid & 255;
    int qh = tid >> 8;                   // 0 or 1
    float bias = bo[h];

    // round 0: q-rows 0..3
    *(float4*)&pout[wave][0][lane << 2] = acc0;
    *(float4*)&pout[wave][1][lane << 2] = acc1;
    *(float4*)&pout[wave][2][lane << 2] = acc2;
    *(float4*)&pout[wave][3][lane << 2] = acc3;
    __syncthreads();
    #pragma unroll
    for (int qq = 0; qq < 2; ++qq) {
        int qi = qh * 2 + qq;
        float s = bias;
        #pragma unroll
        for (int w2 = 0; w2 < 8; ++w2) s += pout[w2][qi][h];
        out[(size_t)(b * SQL + q0 + qi) * HH + h] = s;
    }
    __syncthreads();

    // round 1: q-rows 4..7
    *(float4*)&pout[wave][0][lane << 2] = acc4;
    *(float4*)&pout[wave][1][lane << 2] = acc5;
    *(float4*)&pout[wave][2][lane << 2] = acc6;
    *(float4*)&pout[wave][3][lane << 2] = acc7;
    __syncthreads();
    #pragma unroll
    for (int qq = 0; qq < 2; ++qq) {
        int qi = qh * 2 + qq;
        float s = bias;
        #pragma unroll
        for (int w2 = 0; w2 < 8; ++w2) s += pout[w2][qi][h];
        out[(size_t)(b * SQL + q0 + 4 + qi) * HH + h] = s;
    }
}

// ---------------------------------------------------------------------------
extern "C" void kernel_launch(void* const* d_in, const int* in_sizes, int n_in,
                              void* d_out, int out_size, void* d_ws, size_t ws_size,
                              hipStream_t stream)
{
    const float* Q  = (const float*)d_in[0];
    const float* K  = (const float*)d_in[1];
    const float* V  = (const float*)d_in[2];
    const float* Wq = (const float*)d_in[3];
    const float* Wk = (const float*)d_in[4];
    const float* v  = (const float*)d_in[5];
    const float* Wo = (const float*)d_in[6];
    const float* bo = (const float*)d_in[7];

    float* out     = (float*)d_out;                   // (B,SQ,H) = 524288
    float* weights = out + (size_t)BB * SQL * HH;     // (B,SQ,SK) = 1048576

    float* Qt = (float*)d_ws;                         // 262144 floats
    float* Kt = Qt + (size_t)BB * SQL * AA;           // 262144 floats
    float* VW = Kt + (size_t)BB * SKL * AA;           // 524288 floats

    prep_kernel <<<512, 256, 0, stream>>>(Q, K, V, Wq, Wk, Wo, Qt, Kt, VW);
    score_kernel<<<256, 512, 0, stream>>>(Qt, Kt, v, VW, bo, weights, out);
}

// Round 10
// 117.968 us; speedup vs baseline: 1.0151x; 1.0151x over previous
//
#include <hip/hip_runtime.h>
#include <math.h>

#define BB 4
#define SQL 512
#define SKL 512
#define HH 256
#define AA 128

// 2 * log2(e): Qt/Kt pre-scaled so the score loop feeds v_exp_f32 (2^x) directly.
#define PRESCALE 2.8853900817779268f
#define LOG2E    1.4426950408889634f

__device__ inline void fma4(float4& a, float s, const float4& b) {
    a.x = fmaf(s, b.x, a.x); a.y = fmaf(s, b.y, a.y);
    a.z = fmaf(s, b.z, a.z); a.w = fmaf(s, b.w, a.w);
}

// DPP add: x + dpp_move(x). Stays on the VALU pipe (no ds_swizzle / lgkm).
template <int CTRL>
__device__ __forceinline__ float dpp_add(float x) {
    int m = __builtin_amdgcn_update_dpp(__float_as_int(x), __float_as_int(x),
                                        CTRL, 0xF, 0xF, false);
    return x + __int_as_float(m);
}
// Sum over each aligned 16-lane group (one DPP row):
//   xor1 = quad_perm:[1,0,3,2] (0xB1), xor2 = quad_perm:[2,3,0,1] (0x4E),
//   xor4 = row_half_mirror (0x141), xor8 = row_mirror (0x140).
__device__ __forceinline__ float red16(float x) {
    x = dpp_add<0xB1>(x);
    x = dpp_add<0x4E>(x);
    x = dpp_add<0x141>(x);
    x = dpp_add<0x140>(x);
    return x;
}

// ---------------------------------------------------------------------------
// Kernel 1 "prep": Qt = PRESCALE*(Q@W_q), Kt = PRESCALE*(K@W_k), VW = V@W_o.
// (unchanged from verified version)
// ---------------------------------------------------------------------------
__global__ __launch_bounds__(256) void prep_kernel(
    const float* __restrict__ Q, const float* __restrict__ K,
    const float* __restrict__ V,
    const float* __restrict__ Wq, const float* __restrict__ Wk,
    const float* __restrict__ Wo,
    float* __restrict__ Qt, float* __restrict__ Kt, float* __restrict__ VW)
{
    __shared__ float rows[16 * HH];    // 16 KB
    __shared__ float wl[64 * 128];     // 32 KB
    int tid = threadIdx.x;
    int bid = blockIdx.x;

    const float* X; const float* W; float* Y;
    int ldW, ldY, col0, r0; float scale;
    if (bid < 128)      { X=Q; W=Wq; Y=Qt; ldW=AA; ldY=AA; col0=0; r0=bid*16;       scale=PRESCALE; }
    else if (bid < 256) { X=K; W=Wk; Y=Kt; ldW=AA; ldY=AA; col0=0; r0=(bid-128)*16; scale=PRESCALE; }
    else { int b2=bid-256; X=V; W=Wo; Y=VW; ldW=HH; ldY=HH; col0=(b2&1)*128; r0=(b2>>1)*16; scale=1.0f; }

    {
        const float4* Xv = (const float4*)(X + (size_t)r0 * HH);
        float4* rv = (float4*)rows;
        rv[tid]       = Xv[tid];
        rv[tid + 256] = Xv[tid + 256];
        rv[tid + 512] = Xv[tid + 512];
        rv[tid + 768] = Xv[tid + 768];
    }

    int r  = tid >> 5;
    int c4 = tid & 31;
    float4 accA = {0.f,0.f,0.f,0.f}, accB = {0.f,0.f,0.f,0.f};

    for (int ch = 0; ch < 4; ++ch) {
        __syncthreads();
        {
            const float* Wbase = W + (size_t)(ch * 64) * ldW + col0;
            float4* wv = (float4*)wl;
            #pragma unroll
            for (int it = 0; it < 8; ++it) {
                int l = tid + it * 256;
                wv[l] = *(const float4*)(Wbase + (size_t)(l >> 5) * ldW + ((l & 31) << 2));
            }
        }
        __syncthreads();
        const float* rrowA = rows + r * HH + ch * 64;
        const float* rrowB = rows + (r + 8) * HH + ch * 64;
        #pragma unroll 4
        for (int h4 = 0; h4 < 16; ++h4) {
            float4 ra = *(const float4*)(rrowA + h4 * 4);
            float4 rb = *(const float4*)(rrowB + h4 * 4);
            const float* wbase = wl + (h4 * 4) * 128 + (c4 << 2);
            float4 w0 = *(const float4*)(wbase);
            float4 w1 = *(const float4*)(wbase + 128);
            float4 w2 = *(const float4*)(wbase + 256);
            float4 w3 = *(const float4*)(wbase + 384);
            fma4(accA, ra.x, w0); fma4(accA, ra.y, w1);
            fma4(accA, ra.z, w2); fma4(accA, ra.w, w3);
            fma4(accB, rb.x, w0); fma4(accB, rb.y, w1);
            fma4(accB, rb.z, w2); fma4(accB, rb.w, w3);
        }
    }
    accA.x *= scale; accA.y *= scale; accA.z *= scale; accA.w *= scale;
    accB.x *= scale; accB.y *= scale; accB.z *= scale; accB.w *= scale;
    *(float4*)(Y + (size_t)(r0 + r)     * ldY + col0 + (c4 << 2)) = accA;
    *(float4*)(Y + (size_t)(r0 + r + 8) * ldY + col0 + (c4 << 2)) = accB;
}

// ---------------------------------------------------------------------------
// Kernel 2: fused scores + softmax + (weights @ VW + b_o).
// grid = B*SQ/8 = 256 blocks x 512 thr (8 waves). 8 q-rows per block.
//   score[q][k] = S_all - sum_a 2*v[a] * rcp(Ek*Eq + 1),  Ek=2^kt, Eq=2^qt.
// R7 post-mortem: VGPR_Count=68 despite ~106+ mandatory live floats -> the
// allocator targeted ~7 waves/EU and REMATERIALIZED/spilled Eq (reloading
// Qt + recomputing exp2 per chunk). Grid is 1 block/CU (and LDS caps at 3),
// so that occupancy target buys nothing and costs ~3x in loop latency.
// amdgpu_waves_per_eu(2,2) pins the occupancy assumption: budget = 256 VGPR,
// no reward for staying small -> Eq's 64 floats stay live in registers.
// ---------------------------------------------------------------------------
#define FORQ(OP) OP(0) OP(1) OP(2) OP(3) OP(4) OP(5) OP(6) OP(7)

__global__ __launch_bounds__(512)
__attribute__((amdgpu_waves_per_eu(2, 2)))
void score_kernel(
    const float* __restrict__ Qt, const float* __restrict__ Kt,
    const float* __restrict__ v,  const float* __restrict__ VW,
    const float* __restrict__ bo,
    float* __restrict__ weights,  float* __restrict__ out)
{
    __shared__ float score[8][SKL];      // 16 KB
    __shared__ float pout[8][4][HH];     // 32 KB   (total 48 KB)

    int tid = threadIdx.x;
    int b  = blockIdx.x >> 6;            // 64 blocks per batch
    int q0 = (blockIdx.x & 63) << 3;     // 8 q-rows per block
    int ag = tid & 15;                   // a-range [8ag, 8ag+8)
    int kl = tid >> 4;                   // k within 32-chunk (0..31)

    // 2*v fragment: 8 floats in 2 named float4
    float4 v2a, v2b;
    {
        const float4* vp = (const float4*)(v + ag * 8);
        v2a = vp[0]; v2b = vp[1];
        v2a.x *= 2.f; v2a.y *= 2.f; v2a.z *= 2.f; v2a.w *= 2.f;
        v2b.x *= 2.f; v2b.y *= 2.f; v2b.z *= 2.f; v2b.w *= 2.f;
    }

    // Eq = 2^(Qt prescaled): 8 q-rows x 8 a -> 16 named float4
#define DECL_EQ(Qi) float4 EqA##Qi, EqB##Qi;
    FORQ(DECL_EQ)
#define LOAD_EQ(Qi) { \
        const float4* qp = (const float4*)(Qt + (size_t)(b * SQL + q0 + Qi) * AA + ag * 8); \
        float4 t0 = qp[0], t1 = qp[1]; \
        (EqA##Qi).x = __builtin_amdgcn_exp2f(t0.x); (EqA##Qi).y = __builtin_amdgcn_exp2f(t0.y); \
        (EqA##Qi).z = __builtin_amdgcn_exp2f(t0.z); (EqA##Qi).w = __builtin_amdgcn_exp2f(t0.w); \
        (EqB##Qi).x = __builtin_amdgcn_exp2f(t1.x); (EqB##Qi).y = __builtin_amdgcn_exp2f(t1.y); \
        (EqB##Qi).z = __builtin_amdgcn_exp2f(t1.z); (EqB##Qi).w = __builtin_amdgcn_exp2f(t1.w); }
    FORQ(LOAD_EQ)

    // S_all = sum_a v[a]  (v2 = 2v, so 0.5 * red16)
    float S_all;
    {
        float ls = (v2a.x + v2a.y) + (v2a.z + v2a.w)
                 + (v2b.x + v2b.y) + (v2b.z + v2b.w);
        S_all = 0.5f * red16(ls);
    }

    const float4* ktp = (const float4*)(Kt + (size_t)b * SKL * AA);

    // ---- main loop: 16 chunks x 32 k-rows; named-reg prefetch ----
    {
        float4 ka = ktp[(size_t)kl * (AA / 4) + ag * 2];
        float4 kb = ktp[(size_t)kl * (AA / 4) + ag * 2 + 1];
        #pragma unroll 1
        for (int c = 0; c < 16; ++c) {
            float4 na, nb;
            if (c < 15) {
                int kn = (c + 1) * 32 + kl;
                na = ktp[(size_t)kn * (AA / 4) + ag * 2];
                nb = ktp[(size_t)kn * (AA / 4) + ag * 2 + 1];
            }
#define DECL_P(Qi) float p##Qi = 0.f;
            FORQ(DECL_P)
#define STEP(KE, VE, HB, COMP) { \
            float Ek = __builtin_amdgcn_exp2f(KE); \
            p0 = fmaf(VE, __builtin_amdgcn_rcpf(fmaf(Ek, (Eq##HB##0).COMP, 1.0f)), p0); \
            p1 = fmaf(VE, __builtin_amdgcn_rcpf(fmaf(Ek, (Eq##HB##1).COMP, 1.0f)), p1); \
            p2 = fmaf(VE, __builtin_amdgcn_rcpf(fmaf(Ek, (Eq##HB##2).COMP, 1.0f)), p2); \
            p3 = fmaf(VE, __builtin_amdgcn_rcpf(fmaf(Ek, (Eq##HB##3).COMP, 1.0f)), p3); \
            p4 = fmaf(VE, __builtin_amdgcn_rcpf(fmaf(Ek, (Eq##HB##4).COMP, 1.0f)), p4); \
            p5 = fmaf(VE, __builtin_amdgcn_rcpf(fmaf(Ek, (Eq##HB##5).COMP, 1.0f)), p5); \
            p6 = fmaf(VE, __builtin_amdgcn_rcpf(fmaf(Ek, (Eq##HB##6).COMP, 1.0f)), p6); \
            p7 = fmaf(VE, __builtin_amdgcn_rcpf(fmaf(Ek, (Eq##HB##7).COMP, 1.0f)), p7); }
            STEP(ka.x, v2a.x, A, x) STEP(ka.y, v2a.y, A, y)
            STEP(ka.z, v2a.z, A, z) STEP(ka.w, v2a.w, A, w)
            STEP(kb.x, v2b.x, B, x) STEP(kb.y, v2b.y, B, y)
            STEP(kb.z, v2b.z, B, z) STEP(kb.w, v2b.w, B, w)
#define RED_P(Qi) p##Qi = red16(p##Qi);
            FORQ(RED_P)
            if (ag == 0) {
                int k = c * 32 + kl;
#define STORE_P(Qi) score[Qi][k] = (S_all - p##Qi) * LOG2E;
                FORQ(STORE_P)
            }
            ka = na; kb = nb;
        }
    }
    __syncthreads();

    // ---- softmax (no max pass: |score| bounded by sum|2v| ~ 11.3 nat) ----
    int wave = tid >> 6, lane = tid & 63;
    {
        int qi = wave;                   // 8 waves, one q-row each
        float ssum = 0.f;
        #pragma unroll
        for (int it = 0; it < 2; ++it) {
            int k0 = it * 256 + (lane << 2);
            float4 sv = *(float4*)&score[qi][k0];
            sv.x = __builtin_amdgcn_exp2f(sv.x);
            sv.y = __builtin_amdgcn_exp2f(sv.y);
            sv.z = __builtin_amdgcn_exp2f(sv.z);
            sv.w = __builtin_amdgcn_exp2f(sv.w);
            *(float4*)&score[qi][k0] = sv;
            ssum += (sv.x + sv.y) + (sv.z + sv.w);
        }
        #pragma unroll
        for (int off = 32; off; off >>= 1) ssum += __shfl_xor(ssum, off);
        float rinv = 1.0f / ssum;
        size_t rowoff = (size_t)(b * SQL + q0 + qi) * SKL;
        #pragma unroll
        for (int it = 0; it < 2; ++it) {
            int k0 = it * 256 + (lane << 2);
            float4 sv = *(float4*)&score[qi][k0];
            sv.x *= rinv; sv.y *= rinv; sv.z *= rinv; sv.w *= rinv;
            *(float4*)&score[qi][k0] = sv;
            *(float4*)(weights + rowoff + k0) = sv;
        }
    }
    __syncthreads();

    // ---- epilogue: wave w owns k in [64w, 64w+64); one VW pass serves 8 q
#define DECL_ACC(Qi) float4 acc##Qi = {0.f, 0.f, 0.f, 0.f};
    FORQ(DECL_ACC)
    {
        const float4* VWb = (const float4*)(VW + (size_t)b * SKL * HH);
        int kbase = wave * 64;
        #pragma unroll 2
        for (int k4 = 0; k4 < 16; ++k4) {
            int kk = kbase + k4 * 4;
#define DECL_W(Qi) float4 w##Qi = *(const float4*)&score[Qi][kk];
            FORQ(DECL_W)
            float4 vw;
            vw = VWb[(size_t)(kk + 0) * (HH / 4) + lane];
#define FMA_X(Qi) fma4(acc##Qi, (w##Qi).x, vw);
            FORQ(FMA_X)
            vw = VWb[(size_t)(kk + 1) * (HH / 4) + lane];
#define FMA_Y(Qi) fma4(acc##Qi, (w##Qi).y, vw);
            FORQ(FMA_Y)
            vw = VWb[(size_t)(kk + 2) * (HH / 4) + lane];
#define FMA_Z(Qi) fma4(acc##Qi, (w##Qi).z, vw);
            FORQ(FMA_Z)
            vw = VWb[(size_t)(kk + 3) * (HH / 4) + lane];
#define FMA_W(Qi) fma4(acc##Qi, (w##Qi).w, vw);
            FORQ(FMA_W)
        }
    }

    // ---- LDS tree-reduce over the 8 waves, 2 rounds of 4 q-rows ----
    int h  = tid & 255;
    int qh = tid >> 8;                   // 0 or 1
    float bias = bo[h];

    // round 0: q-rows 0..3
    *(float4*)&pout[wave][0][lane << 2] = acc0;
    *(float4*)&pout[wave][1][lane << 2] = acc1;
    *(float4*)&pout[wave][2][lane << 2] = acc2;
    *(float4*)&pout[wave][3][lane << 2] = acc3;
    __syncthreads();
    #pragma unroll
    for (int qq = 0; qq < 2; ++qq) {
        int qi = qh * 2 + qq;
        float s = bias;
        #pragma unroll
        for (int w2 = 0; w2 < 8; ++w2) s += pout[w2][qi][h];
        out[(size_t)(b * SQL + q0 + qi) * HH + h] = s;
    }
    __syncthreads();

    // round 1: q-rows 4..7
    *(float4*)&pout[wave][0][lane << 2] = acc4;
    *(float4*)&pout[wave][1][lane << 2] = acc5;
    *(float4*)&pout[wave][2][lane << 2] = acc6;
    *(float4*)&pout[wave][3][lane << 2] = acc7;
    __syncthreads();
    #pragma unroll
    for (int qq = 0; qq < 2; ++qq) {
        int qi = qh * 2 + qq;
        float s = bias;
        #pragma unroll
        for (int w2 = 0; w2 < 8; ++w2) s += pout[w2][qi][h];
        out[(size_t)(b * SQL + q0 + 4 + qi) * HH + h] = s;
    }
}

// ---------------------------------------------------------------------------
extern "C" void kernel_launch(void* const* d_in, const int* in_sizes, int n_in,
                              void* d_out, int out_size, void* d_ws, size_t ws_size,
                              hipStream_t stream)
{
    const float* Q  = (const float*)d_in[0];
    const float* K  = (const float*)d_in[1];
    const float* V  = (const float*)d_in[2];
    const float* Wq = (const float*)d_in[3];
    const float* Wk = (const float*)d_in[4];
    const float* v  = (const float*)d_in[5];
    const float* Wo = (const float*)d_in[6];
    const float* bo = (const float*)d_in[7];

    float* out     = (float*)d_out;                   // (B,SQ,H) = 524288
    float* weights = out + (size_t)BB * SQL * HH;     // (B,SQ,SK) = 1048576

    float* Qt = (float*)d_ws;                         // 262144 floats
    float* Kt = Qt + (size_t)BB * SQL * AA;           // 262144 floats
    float* VW = Kt + (size_t)BB * SKL * AA;           // 524288 floats

    prep_kernel <<<512, 256, 0, stream>>>(Q, K, V, Wq, Wk, Wo, Qt, Kt, VW);
    score_kernel<<<256, 512, 0, stream>>>(Qt, Kt, v, VW, bo, weights, out);
}